// Round 2
// baseline (174.156 us; speedup 1.0000x reference)
//
#include <hip/hip_runtime.h>
#include <hip/hip_bf16.h>

#define N_NODES 4096
#define DIN     512
#define FDIM    64
#define NHEADS  8
#define DOUT    16
#define MAXN    512

typedef __attribute__((ext_vector_type(8))) short bf16x8;
typedef __attribute__((ext_vector_type(4))) float f32x4;

static __device__ __forceinline__ float us2f(unsigned short u) {
    union { unsigned int i; float f; } cv; cv.i = ((unsigned int)u) << 16; return cv.f;
}
static __device__ __forceinline__ unsigned short f2us(float v) {
    __hip_bfloat16 b = __float2bfloat16(v);
    return *(const unsigned short*)&b;
}
// dtype: adj[0][0] is a guaranteed self-loop 1.0; fp32 1.0f low ushort = 0 (verified r4-r11)
static __device__ __forceinline__ int is_f32(const void* adj) {
    return (((const unsigned short*)adj)[0] == 0) ? 1 : 0;
}

// ---------------------------------------------------------------------------
// K0: prep only (1024 blocks). Neighbor-list scan moved into attn1_fused so the
// 64 MB adjacency HBM stream overlaps attn1's L2 gather instead of serializing.
// Writes: Xb bf16, Wt[h][f][d] bf16, Woc fp32 (for fused who), small vecs fp32.
// ---------------------------------------------------------------------------
__global__ __launch_bounds__(256) void prep_kernel(
    const void* __restrict__ adj, const void* __restrict__ X, const void* __restrict__ W,
    const void* __restrict__ a1, const void* __restrict__ a2, const void* __restrict__ Wo,
    const void* __restrict__ ao1, const void* __restrict__ ao2,
    unsigned short* __restrict__ Xb, unsigned short* __restrict__ Wt,
    float* __restrict__ Woc,
    float* __restrict__ a1c, float* __restrict__ a2c,
    float* __restrict__ ao1c, float* __restrict__ ao2c)
{
    const int f32 = is_f32(adj);
    const int i0 = blockIdx.x * 256 + threadIdx.x;
    const int T = 1024 * 256;
    for (int i = i0; i < N_NODES * DIN; i += T) {
        float v = f32 ? ((const float*)X)[i] : us2f(((const unsigned short*)X)[i]);
        Xb[i] = f2us(v);
    }
    for (int i = i0; i < NHEADS * DIN * FDIM; i += T) {
        int hh = i >> 15, rem = i & 32767, d = rem >> 6, f = rem & 63;
        float v = f32 ? ((const float*)W)[i] : us2f(((const unsigned short*)W)[i]);
        Wt[((size_t)(hh * FDIM + f)) * DIN + d] = f2us(v);
    }
    if (i0 < DIN * DOUT) {
        float v = f32 ? ((const float*)Wo)[i0] : us2f(((const unsigned short*)Wo)[i0]);
        Woc[i0] = v;   // row-major [d][j], fp32 (fused who dot is full fp32)
    }
    if (i0 < 512) {
        a1c[i0] = f32 ? ((const float*)a1)[i0] : us2f(((const unsigned short*)a1)[i0]);
        a2c[i0] = f32 ? ((const float*)a2)[i0] : us2f(((const unsigned short*)a2)[i0]);
    }
    if (i0 < 16) {
        ao1c[i0] = f32 ? ((const float*)ao1)[i0] : us2f(((const unsigned short*)ao1)[i0]);
        ao2c[i0] = f32 ? ((const float*)ao2)[i0] : us2f(((const unsigned short*)ao2)[i0]);
    }
}

// ---------------------------------------------------------------------------
// K1: MFMA GEMM with SWAPPED operands (D = Wt · X^T): lane l16 = node, register
// quad = 4 consecutive f. Packed 8 B Whb stores (4/wave vs 16 scalar 2 B), and
// f1/f2 become lane-local dots (2 shuffles, coalesced 64 B writes).
// A/B fragment layouts symmetric: A row = lane&15, B col = lane&15, k=(lane>>4)*8+e.
// ---------------------------------------------------------------------------
__global__ __launch_bounds__(256) void wh_f12_kernel(
    const unsigned short* __restrict__ Xb, const unsigned short* __restrict__ Wt,
    const float* __restrict__ a1c, const float* __restrict__ a2c,
    unsigned short* __restrict__ Whb, float* __restrict__ f1, float* __restrict__ f2)
{
    const int h  = blockIdx.x;
    const int bm = blockIdx.y;
    const int w    = threadIdx.x >> 6;
    const int lane = threadIdx.x & 63;
    const int quad = lane >> 4;
    const int l16  = lane & 15;
    const int node = bm * 64 + w * 16 + l16;   // D col = l16 -> node index

    f32x4 acc[4];
#pragma unroll
    for (int j = 0; j < 4; ++j) acc[j] = (f32x4){0.f, 0.f, 0.f, 0.f};

    const unsigned short* xp = Xb + (size_t)node * DIN + quad * 8;           // B-frag: X^T col = node
    const unsigned short* wp = Wt + (size_t)h * FDIM * DIN + quad * 8;       // A-frag: Wt row = f
#pragma unroll 4
    for (int k0 = 0; k0 < DIN; k0 += 32) {
        bf16x8 b = *(const bf16x8*)(xp + k0);
#pragma unroll
        for (int j = 0; j < 4; ++j) {
            bf16x8 a = *(const bf16x8*)(wp + (size_t)(j * 16 + l16) * DIN + k0);
            acc[j] = __builtin_amdgcn_mfma_f32_16x16x32_bf16(a, b, acc[j], 0, 0, 0);
        }
    }
    // D layout: col(=node)=lane&15, row(=f within 16-tile)=quad*4+rr  [m89-verified]
    float p1 = 0.f, p2 = 0.f;
#pragma unroll
    for (int j = 0; j < 4; ++j) {
        const int fbase = j * 16 + quad * 4;
        ushort4 st;
        st.x = f2us(acc[j][0]); st.y = f2us(acc[j][1]);
        st.z = f2us(acc[j][2]); st.w = f2us(acc[j][3]);
        *(ushort4*)&Whb[((size_t)node * NHEADS + h) * FDIM + fbase] = st;   // packed 8 B store
#pragma unroll
        for (int rr = 0; rr < 4; ++rr) {
            p1 += acc[j][rr] * a1c[h * FDIM + fbase + rr];
            p2 += acc[j][rr] * a2c[h * FDIM + fbase + rr];
        }
    }
    // reduce over the 4 quads (f-rows split across quads)
    p1 += __shfl_xor(p1, 16); p1 += __shfl_xor(p1, 32);
    p2 += __shfl_xor(p2, 16); p2 += __shfl_xor(p2, 32);
    if (quad == 0) {
        f1[h * N_NODES + node] = p1;   // 16 lanes -> coalesced 64 B
        f2[h * N_NODES + node] = p2;
    }
}

// ---------------------------------------------------------------------------
// K2: FUSED layer-1 attention: adjacency-row scan + compaction (persisted to
// cnt/nbr for attn2), softmax, wave-per-row uint4 gather (16 B/lane, 4 rows per
// iteration), ELU, then the fused output projection Who = cat @ Wo (fp32) and
// g1/g2 — eliminates the old K3 dispatch and the catb bf16 global roundtrip.
// ---------------------------------------------------------------------------
__global__ __launch_bounds__(256) void attn1_fused_kernel(
    const void* __restrict__ adj,
    const unsigned short* __restrict__ Whb,
    const float* __restrict__ f1, const float* __restrict__ f2,
    const float* __restrict__ Woc,
    const float* __restrict__ ao1c, const float* __restrict__ ao2c,
    int* __restrict__ cnt, int* __restrict__ nbr,
    float* __restrict__ Who, float* __restrict__ g1, float* __restrict__ g2)
{
    const int n   = blockIdx.x;
    const int tid = threadIdx.x;
    const int wv  = tid >> 6;
    const int lane = tid & 63;

    __shared__ int   sh_m[MAXN];
    __shared__ int   sh_c;
    __shared__ float sh_s[NHEADS][516];     // softmax weights (padded stride 516)
    __shared__ float sh_inv[NHEADS];
    __shared__ float sh_red[3][64][9];      // cross-wave gather reduction (pad 9: conflict-free)
    __shared__ float cat_sh[512];           // fp32 cat row
    __shared__ float sh_p[16 * 17];         // who partials (pad 17)

    // ---- phase 1: scan own adjacency row, compact neighbor list ----
    if (tid == 0) sh_c = 0;
    __syncthreads();
    if (is_f32(adj)) {
        const uint4* row = (const uint4*)((const unsigned int*)adj + (size_t)n * N_NODES);
#pragma unroll 4
        for (int q = tid; q < N_NODES / 4; q += 256) {
            uint4 v = row[q];
            int base = q * 4;
            if (v.x) { int p = atomicAdd(&sh_c, 1); if (p < MAXN) sh_m[p] = base + 0; }
            if (v.y) { int p = atomicAdd(&sh_c, 1); if (p < MAXN) sh_m[p] = base + 1; }
            if (v.z) { int p = atomicAdd(&sh_c, 1); if (p < MAXN) sh_m[p] = base + 2; }
            if (v.w) { int p = atomicAdd(&sh_c, 1); if (p < MAXN) sh_m[p] = base + 3; }
        }
    } else {
        const ushort4* row = (const ushort4*)((const unsigned short*)adj + (size_t)n * N_NODES);
#pragma unroll 4
        for (int q = tid; q < N_NODES / 4; q += 256) {
            ushort4 v = row[q];
            int base = q * 4;
            if (v.x) { int p = atomicAdd(&sh_c, 1); if (p < MAXN) sh_m[p] = base + 0; }
            if (v.y) { int p = atomicAdd(&sh_c, 1); if (p < MAXN) sh_m[p] = base + 1; }
            if (v.z) { int p = atomicAdd(&sh_c, 1); if (p < MAXN) sh_m[p] = base + 2; }
            if (v.w) { int p = atomicAdd(&sh_c, 1); if (p < MAXN) sh_m[p] = base + 3; }
        }
    }
    __syncthreads();
    const int c = (sh_c < MAXN) ? sh_c : MAXN;
    for (int k = tid; k < c; k += 256) nbr[(size_t)n * MAXN + k] = sh_m[k];  // persist for attn2
    if (tid == 0) cnt[n] = c;

    // ---- phase 2: per-head softmax over neighbors (8 heads x 32 lanes) ----
    const int h = tid >> 5;
    const int l32 = tid & 31;
    const float f1v = f1[h * N_NODES + n];
    float mx = -1e30f;
    for (int k = l32; k < c; k += 32) {
        float s = f1v + f2[h * N_NODES + sh_m[k]];
        s = (s >= 0.f) ? s : 0.2f * s;              // LeakyReLU(0.2)
        sh_s[h][k] = s;
        mx = fmaxf(mx, s);
    }
#pragma unroll
    for (int off = 16; off; off >>= 1) mx = fmaxf(mx, __shfl_xor(mx, off));
    float sum = 0.f;
    for (int k = l32; k < c; k += 32) {
        float e = __expf(sh_s[h][k] - mx);
        sh_s[h][k] = e;
        sum += e;
    }
#pragma unroll
    for (int off = 16; off; off >>= 1) sum += __shfl_xor(sum, off);
    if (l32 == 0) sh_inv[h] = (sum > 0.f) ? 1.f / sum : 0.f;
    __syncthreads();

    // ---- phase 3: gather — wave wv handles row k=kb+wv, full 1 KB row per wave,
    // 16 B/lane uint4 (4x fewer load instrs than 4 B/lane). lane: head=lane>>3,
    // f-range=(lane&7)*8 .. +8 -> 8 fp32 accumulators per lane.
    const int hh = lane >> 3;
    float acc8[8];
#pragma unroll
    for (int e = 0; e < 8; ++e) acc8[e] = 0.f;
    const uint4* wb = (const uint4*)Whb;
#pragma unroll 2
    for (int kb = 0; kb < c; kb += 4) {
        const int k = kb + wv;                  // wave-uniform guard, no divergence
        float wgt = 0.f; int m = sh_m[0];
        if (k < c) { wgt = sh_s[hh][k]; m = sh_m[k]; }
        uint4 v = wb[(size_t)m * 64 + lane];
        acc8[0] += wgt * us2f((unsigned short)(v.x & 0xFFFFu));
        acc8[1] += wgt * us2f((unsigned short)(v.x >> 16));
        acc8[2] += wgt * us2f((unsigned short)(v.y & 0xFFFFu));
        acc8[3] += wgt * us2f((unsigned short)(v.y >> 16));
        acc8[4] += wgt * us2f((unsigned short)(v.z & 0xFFFFu));
        acc8[5] += wgt * us2f((unsigned short)(v.z >> 16));
        acc8[6] += wgt * us2f((unsigned short)(v.w & 0xFFFFu));
        acc8[7] += wgt * us2f((unsigned short)(v.w >> 16));
    }
    if (wv) {
#pragma unroll
        for (int e = 0; e < 8; ++e) sh_red[wv - 1][lane][e] = acc8[e];
    }
    __syncthreads();
    if (wv == 0) {
        const float inv = sh_inv[hh];
#pragma unroll
        for (int e = 0; e < 8; ++e) {
            float s = acc8[e] + sh_red[0][lane][e] + sh_red[1][lane][e] + sh_red[2][lane][e];
            s *= inv;
            s = (s > 0.f) ? s : expm1f(s);      // ELU
            cat_sh[lane * 8 + e] = s;           // cat[h*64+f] == lane*8+e (fp32!)
        }
    }
    __syncthreads();

    // ---- phase 4: fused Who = cat @ Wo (fp32, 512x16) + g1/g2 ----
    {
        const int j = tid & 15, ch = tid >> 4;  // 16 chunks x 32 d each
        float s = 0.f;
#pragma unroll
        for (int d = 0; d < 32; ++d)
            s += cat_sh[ch * 32 + d] * Woc[(ch * 32 + d) * DOUT + j];  // Wo L1-resident
        sh_p[ch * 17 + j] = s;
    }
    __syncthreads();
    if (tid < 16) {
        float s = 0.f;
#pragma unroll
        for (int ch = 0; ch < 16; ++ch) s += sh_p[ch * 17 + tid];
        Who[n * DOUT + tid] = s;
        float p1 = s * ao1c[tid];
        float p2 = s * ao2c[tid];
#pragma unroll
        for (int off = 8; off; off >>= 1) {
            p1 += __shfl_xor(p1, off);
            p2 += __shfl_xor(p2, off);
        }
        if (tid == 0) { g1[n] = p1; g2[n] = p2; }
    }
}

// ---------------------------------------------------------------------------
// K3: output sparse attention (unchanged; verified r9-r11); fp32/bf16 store.
// ---------------------------------------------------------------------------
__global__ __launch_bounds__(64) void attn2_kernel(
    const void* __restrict__ adj,
    const float* __restrict__ Who,
    const float* __restrict__ g1, const float* __restrict__ g2,
    const int* __restrict__ cnt, const int* __restrict__ nbr,
    void* __restrict__ out)
{
    const int n = blockIdx.x;
    const int lane = threadIdx.x;
    const int quad = lane >> 4, l16 = lane & 15;
    __shared__ float sh_s[MAXN];
    __shared__ int sh_m[MAXN];
    const int c0 = cnt[n];
    const int c = (c0 < MAXN) ? c0 : MAXN;
    for (int k = lane; k < c; k += 64) sh_m[k] = nbr[(size_t)n * MAXN + k];
    __syncthreads();
    const float gn = g1[n];
    float mx = -1e30f;
    for (int k = lane; k < c; k += 64) {
        float s = gn + g2[sh_m[k]];
        s = (s >= 0.f) ? s : 0.2f * s;
        sh_s[k] = s;
        mx = fmaxf(mx, s);
    }
#pragma unroll
    for (int off = 32; off; off >>= 1) mx = fmaxf(mx, __shfl_xor(mx, off));
    __syncthreads();
    float sum = 0.f;
    for (int k = lane; k < c; k += 64) {
        float e = __expf(sh_s[k] - mx);
        sh_s[k] = e;
        sum += e;
    }
#pragma unroll
    for (int off = 32; off; off >>= 1) sum += __shfl_xor(sum, off);
    __syncthreads();
    const float inv = (sum > 0.f) ? 1.f / sum : 0.f;
    float accv = 0.f;
#pragma unroll 4
    for (int k = quad; k < c; k += 4)
        accv += sh_s[k] * Who[sh_m[k] * DOUT + l16];
    accv += __shfl_xor(accv, 16);
    accv += __shfl_xor(accv, 32);
    if (quad == 0) {
        float v = accv * inv;
        if (is_f32(adj)) ((float*)out)[n * DOUT + l16] = v;
        else             ((unsigned short*)out)[n * DOUT + l16] = f2us(v);
    }
}

__global__ void wsfail_kernel(float* __restrict__ out)
{
    if (threadIdx.x == 0) out[0] = 129.f;
}

// ---------------------------------------------------------------------------
extern "C" void kernel_launch(void* const* d_in, const int* in_sizes, int n_in,
                              void* d_out, int out_size, void* d_ws, size_t ws_size,
                              hipStream_t stream)
{
    const void* adj = d_in[0];
    const void* X   = d_in[1];
    const void* W   = d_in[2];
    const void* a1  = d_in[3];
    const void* a2  = d_in[4];
    const void* Wo  = d_in[5];
    const void* ao1 = d_in[6];
    const void* ao2 = d_in[7];

    const size_t NEEDED = 22000000;
    if (ws_size < NEEDED) { wsfail_kernel<<<1, 64, 0, stream>>>((float*)d_out); return; }

    int*   cnt  = (int*)d_ws;                        // 4096
    int*   nbr  = cnt + 4096;                        // 4096*512
    float* a1c  = (float*)(nbr + 2097152);           // 512
    float* a2c  = a1c + 512;                         // 512
    float* ao1c = a2c + 512;                         // 16
    float* ao2c = ao1c + 16;                         // 16
    float* f1   = ao2c + 16;                         // 32768
    float* f2   = f1 + 32768;                        // 32768
    float* Who  = f2 + 32768;                        // 65536
    float* g1   = Who + 65536;                       // 4096
    float* g2   = g1 + 4096;                         // 4096
    float* Woc  = g2 + 4096;                         // 8192
    unsigned short* Whb = (unsigned short*)(Woc + 8192);  // 2097152
    unsigned short* Xb  = Whb + 2097152;                  // 2097152
    unsigned short* Wt  = Xb + 2097152;                   // 262144

    prep_kernel<<<1024, 256, 0, stream>>>(
        adj, X, W, a1, a2, Wo, ao1, ao2,
        Xb, Wt, Woc, a1c, a2c, ao1c, ao2c);
    wh_f12_kernel<<<dim3(NHEADS, N_NODES / 64), 256, 0, stream>>>(
        Xb, Wt, a1c, a2c, Whb, f1, f2);
    attn1_fused_kernel<<<N_NODES, 256, 0, stream>>>(
        adj, Whb, f1, f2, Woc, ao1c, ao2c, cnt, nbr, Who, g1, g2);
    attn2_kernel<<<N_NODES, 64, 0, stream>>>(adj, Who, g1, g2, cnt, nbr, d_out);
}

// Round 3
// 163.275 us; speedup vs baseline: 1.0666x; 1.0666x over previous
//
#include <hip/hip_runtime.h>
#include <hip/hip_bf16.h>

#define N_NODES 4096
#define DIN     512
#define FDIM    64
#define NHEADS  8
#define DOUT    16
#define MAXN    512

typedef __attribute__((ext_vector_type(8))) short bf16x8;
typedef __attribute__((ext_vector_type(4))) float f32x4;

static __device__ __forceinline__ float us2f(unsigned short u) {
    union { unsigned int i; float f; } cv; cv.i = ((unsigned int)u) << 16; return cv.f;
}
static __device__ __forceinline__ unsigned short f2us(float v) {
    __hip_bfloat16 b = __float2bfloat16(v);
    return *(const unsigned short*)&b;
}
// dtype: adj[0][0] is a guaranteed self-loop 1.0; fp32 1.0f low ushort = 0 (verified r4-r11)
static __device__ __forceinline__ int is_f32(const void* adj) {
    return (((const unsigned short*)adj)[0] == 0) ? 1 : 0;
}

// ---------------------------------------------------------------------------
// K0: prep (blocks 0..1023) + row neighbor lists (blocks 1024..5119) merged —
// round-0 structure restored: the 64 MB adjacency scan runs FIRST, across 4096
// independent blocks, at HBM BW, instead of inside attn1's critical path.
// ---------------------------------------------------------------------------
__global__ __launch_bounds__(256) void prep_nbr_kernel(
    const void* __restrict__ adj, const void* __restrict__ X, const void* __restrict__ W,
    const void* __restrict__ a1, const void* __restrict__ a2, const void* __restrict__ Wo,
    const void* __restrict__ ao1, const void* __restrict__ ao2,
    unsigned short* __restrict__ Xb, unsigned short* __restrict__ Wt,
    float* __restrict__ Woc,
    float* __restrict__ a1c, float* __restrict__ a2c,
    float* __restrict__ ao1c, float* __restrict__ ao2c,
    int* __restrict__ cnt, int* __restrict__ nbr)
{
    const int f32 = is_f32(adj);
    if (blockIdx.x >= 1024) {
        // ---- neighbor list for node n (verified r7-r11) ----
        const int n = blockIdx.x - 1024;
        __shared__ int c;
        if (threadIdx.x == 0) c = 0;
        __syncthreads();
        if (f32) {
            const uint4* row = (const uint4*)((const unsigned int*)adj + (size_t)n * N_NODES);
            for (int q = threadIdx.x; q < N_NODES / 4; q += 256) {
                uint4 v = row[q];
                int base = q * 4;
                if (v.x) { int p = atomicAdd(&c, 1); if (p < MAXN) nbr[(size_t)n * MAXN + p] = base + 0; }
                if (v.y) { int p = atomicAdd(&c, 1); if (p < MAXN) nbr[(size_t)n * MAXN + p] = base + 1; }
                if (v.z) { int p = atomicAdd(&c, 1); if (p < MAXN) nbr[(size_t)n * MAXN + p] = base + 2; }
                if (v.w) { int p = atomicAdd(&c, 1); if (p < MAXN) nbr[(size_t)n * MAXN + p] = base + 3; }
            }
        } else {
            const ushort4* row = (const ushort4*)((const unsigned short*)adj + (size_t)n * N_NODES);
            for (int q = threadIdx.x; q < N_NODES / 4; q += 256) {
                ushort4 v = row[q];
                int base = q * 4;
                if (v.x) { int p = atomicAdd(&c, 1); if (p < MAXN) nbr[(size_t)n * MAXN + p] = base + 0; }
                if (v.y) { int p = atomicAdd(&c, 1); if (p < MAXN) nbr[(size_t)n * MAXN + p] = base + 1; }
                if (v.z) { int p = atomicAdd(&c, 1); if (p < MAXN) nbr[(size_t)n * MAXN + p] = base + 2; }
                if (v.w) { int p = atomicAdd(&c, 1); if (p < MAXN) nbr[(size_t)n * MAXN + p] = base + 3; }
            }
        }
        __syncthreads();
        if (threadIdx.x == 0) cnt[n] = (c < MAXN) ? c : MAXN;
        return;
    }
    // ---- prep (blocks 0..1023) ----
    const int i0 = blockIdx.x * 256 + threadIdx.x;
    const int T = 1024 * 256;
    for (int i = i0; i < N_NODES * DIN; i += T) {
        float v = f32 ? ((const float*)X)[i] : us2f(((const unsigned short*)X)[i]);
        Xb[i] = f2us(v);
    }
    for (int i = i0; i < NHEADS * DIN * FDIM; i += T) {
        int hh = i >> 15, rem = i & 32767, d = rem >> 6, f = rem & 63;
        float v = f32 ? ((const float*)W)[i] : us2f(((const unsigned short*)W)[i]);
        Wt[((size_t)(hh * FDIM + f)) * DIN + d] = f2us(v);
    }
    if (i0 < DIN * DOUT) {
        float v = f32 ? ((const float*)Wo)[i0] : us2f(((const unsigned short*)Wo)[i0]);
        Woc[i0] = v;   // row-major [d][j], fp32 (fused who dot is full fp32)
    }
    if (i0 < 512) {
        a1c[i0] = f32 ? ((const float*)a1)[i0] : us2f(((const unsigned short*)a1)[i0]);
        a2c[i0] = f32 ? ((const float*)a2)[i0] : us2f(((const unsigned short*)a2)[i0]);
    }
    if (i0 < 16) {
        ao1c[i0] = f32 ? ((const float*)ao1)[i0] : us2f(((const unsigned short*)ao1)[i0]);
        ao2c[i0] = f32 ? ((const float*)ao2)[i0] : us2f(((const unsigned short*)ao2)[i0]);
    }
}

// ---------------------------------------------------------------------------
// K1: MFMA GEMM with swapped operands (D = Wt · X^T), packed 8 B Whb stores,
// lane-local f1/f2 dots (verified round 2, absmax 0.00195).
// ---------------------------------------------------------------------------
__global__ __launch_bounds__(256) void wh_f12_kernel(
    const unsigned short* __restrict__ Xb, const unsigned short* __restrict__ Wt,
    const float* __restrict__ a1c, const float* __restrict__ a2c,
    unsigned short* __restrict__ Whb, float* __restrict__ f1, float* __restrict__ f2)
{
    const int h  = blockIdx.x;
    const int bm = blockIdx.y;
    const int w    = threadIdx.x >> 6;
    const int lane = threadIdx.x & 63;
    const int quad = lane >> 4;
    const int l16  = lane & 15;
    const int node = bm * 64 + w * 16 + l16;   // D col = l16 -> node index

    f32x4 acc[4];
#pragma unroll
    for (int j = 0; j < 4; ++j) acc[j] = (f32x4){0.f, 0.f, 0.f, 0.f};

    const unsigned short* xp = Xb + (size_t)node * DIN + quad * 8;           // B-frag: X^T col = node
    const unsigned short* wp = Wt + (size_t)h * FDIM * DIN + quad * 8;       // A-frag: Wt row = f
#pragma unroll 4
    for (int k0 = 0; k0 < DIN; k0 += 32) {
        bf16x8 b = *(const bf16x8*)(xp + k0);
#pragma unroll
        for (int j = 0; j < 4; ++j) {
            bf16x8 a = *(const bf16x8*)(wp + (size_t)(j * 16 + l16) * DIN + k0);
            acc[j] = __builtin_amdgcn_mfma_f32_16x16x32_bf16(a, b, acc[j], 0, 0, 0);
        }
    }
    // D layout: col(=node)=lane&15, row(=f within 16-tile)=quad*4+rr  [m89-verified]
    float p1 = 0.f, p2 = 0.f;
#pragma unroll
    for (int j = 0; j < 4; ++j) {
        const int fbase = j * 16 + quad * 4;
        ushort4 st;
        st.x = f2us(acc[j][0]); st.y = f2us(acc[j][1]);
        st.z = f2us(acc[j][2]); st.w = f2us(acc[j][3]);
        *(ushort4*)&Whb[((size_t)node * NHEADS + h) * FDIM + fbase] = st;   // packed 8 B store
#pragma unroll
        for (int rr = 0; rr < 4; ++rr) {
            p1 += acc[j][rr] * a1c[h * FDIM + fbase + rr];
            p2 += acc[j][rr] * a2c[h * FDIM + fbase + rr];
        }
    }
    p1 += __shfl_xor(p1, 16); p1 += __shfl_xor(p1, 32);
    p2 += __shfl_xor(p2, 16); p2 += __shfl_xor(p2, 32);
    if (quad == 0) {
        f1[h * N_NODES + node] = p1;   // 16 lanes -> coalesced 64 B
        f2[h * N_NODES + node] = p2;
    }
}

// ---------------------------------------------------------------------------
// K2: attn1 with ONLINE softmax fused into the gather (flash-style, defer-max
// threshold 8): no staged sh_s[8][516], no separate softmax phase. Each wave
// handles rows k=kb+wv; per lane: head hh=lane>>3, 8 f-elements. Running
// (m, l) per head per wave; cross-wave merge via exp(m_w - M) coefficients.
// LDS ~12.4 KB -> 8 blocks/CU (32 waves, full occupancy). Fused who + g1/g2.
// ---------------------------------------------------------------------------
__global__ __launch_bounds__(256) void attn1_kernel(
    const unsigned short* __restrict__ Whb,
    const float* __restrict__ f1, const float* __restrict__ f2,
    const float* __restrict__ Woc,
    const float* __restrict__ ao1c, const float* __restrict__ ao2c,
    const int* __restrict__ cnt, const int* __restrict__ nbr,
    float* __restrict__ Who, float* __restrict__ g1, float* __restrict__ g2)
{
    const int n   = blockIdx.x;
    const int tid = threadIdx.x;
    const int wv  = tid >> 6;
    const int lane = tid & 63;
    const int hh = lane >> 3;               // head for this lane

    __shared__ int   sh_m[MAXN];            // 2 KB
    __shared__ float sh_red[3][64][9];      // 6.9 KB cross-wave acc partials (pad 9)
    __shared__ float sh_ml[4][NHEADS][2];   // per-wave per-head (m_ref, l)
    __shared__ float cat_sh[512];           // fp32 cat row
    __shared__ float sh_p[16 * 17];         // who partials (pad 17)

    const int c0 = cnt[n];
    const int c = (c0 < MAXN) ? c0 : MAXN;
    for (int k = tid; k < c; k += 256) sh_m[k] = nbr[(size_t)n * MAXN + k];
    __syncthreads();

    // ---- gather with online softmax ----
    const float f1v = f1[hh * N_NODES + n];
    float m_run = -1e30f, l_run = 0.f;
    float acc8[8];
#pragma unroll
    for (int e = 0; e < 8; ++e) acc8[e] = 0.f;
    const uint4* wb = (const uint4*)Whb;
#pragma unroll 2
    for (int kb = 0; kb < c; kb += 4) {
        const int k = kb + wv;                  // wave-uniform guard
        if (k < c) {
            const int mm = sh_m[k];
            uint4 v = wb[(size_t)mm * 64 + lane];
            float s = f1v + f2[hh * N_NODES + mm];
            s = (s >= 0.f) ? s : 0.2f * s;      // LeakyReLU(0.2)
            if (s > m_run + 8.f) {              // defer-max: rescale rarely
                float scale = __expf(m_run - s);
                l_run *= scale;
#pragma unroll
                for (int e = 0; e < 8; ++e) acc8[e] *= scale;
                m_run = s;
            }
            float wgt = __expf(s - m_run);      // bounded by e^8
            l_run += wgt;
            acc8[0] += wgt * us2f((unsigned short)(v.x & 0xFFFFu));
            acc8[1] += wgt * us2f((unsigned short)(v.x >> 16));
            acc8[2] += wgt * us2f((unsigned short)(v.y & 0xFFFFu));
            acc8[3] += wgt * us2f((unsigned short)(v.y >> 16));
            acc8[4] += wgt * us2f((unsigned short)(v.z & 0xFFFFu));
            acc8[5] += wgt * us2f((unsigned short)(v.z >> 16));
            acc8[6] += wgt * us2f((unsigned short)(v.w & 0xFFFFu));
            acc8[7] += wgt * us2f((unsigned short)(v.w >> 16));
        }
    }
    // publish per-wave state
    if (wv) {
#pragma unroll
        for (int e = 0; e < 8; ++e) sh_red[wv - 1][lane][e] = acc8[e];
    }
    if ((lane & 7) == 0) {
        sh_ml[wv][hh][0] = m_run;
        sh_ml[wv][hh][1] = l_run;
    }
    __syncthreads();
    if (wv == 0) {
        // merge 4 waves for head hh
        float m1 = sh_ml[1][hh][0], m2 = sh_ml[2][hh][0], m3 = sh_ml[3][hh][0];
        float M = fmaxf(fmaxf(m_run, m1), fmaxf(m2, m3));
        float c0f = __expf(m_run - M), c1f = __expf(m1 - M);
        float c2f = __expf(m2 - M),  c3f = __expf(m3 - M);
        float denom = l_run * c0f + sh_ml[1][hh][1] * c1f
                    + sh_ml[2][hh][1] * c2f + sh_ml[3][hh][1] * c3f;
        const float inv = (denom > 0.f) ? 1.f / denom : 0.f;
#pragma unroll
        for (int e = 0; e < 8; ++e) {
            float s = acc8[e] * c0f + sh_red[0][lane][e] * c1f
                    + sh_red[1][lane][e] * c2f + sh_red[2][lane][e] * c3f;
            s *= inv;
            s = (s > 0.f) ? s : expm1f(s);      // ELU
            cat_sh[lane * 8 + e] = s;           // cat[h*64+f] == lane*8+e (fp32)
        }
    }
    __syncthreads();

    // ---- fused Who = cat @ Wo (fp32, 512x16) + g1/g2 ----
    {
        const int j = tid & 15, ch = tid >> 4;  // 16 chunks x 32 d each
        float s = 0.f;
#pragma unroll
        for (int d = 0; d < 32; ++d)
            s += cat_sh[ch * 32 + d] * Woc[(ch * 32 + d) * DOUT + j];  // Wo L1-resident
        sh_p[ch * 17 + j] = s;
    }
    __syncthreads();
    if (tid < 16) {
        float s = 0.f;
#pragma unroll
        for (int ch = 0; ch < 16; ++ch) s += sh_p[ch * 17 + tid];
        Who[n * DOUT + tid] = s;
        float p1 = s * ao1c[tid];
        float p2 = s * ao2c[tid];
#pragma unroll
        for (int off = 8; off; off >>= 1) {
            p1 += __shfl_xor(p1, off);
            p2 += __shfl_xor(p2, off);
        }
        if (tid == 0) { g1[n] = p1; g2[n] = p2; }
    }
}

// ---------------------------------------------------------------------------
// K3: output sparse attention (unchanged; verified); fp32/bf16 store per dtype.
// ---------------------------------------------------------------------------
__global__ __launch_bounds__(64) void attn2_kernel(
    const void* __restrict__ adj,
    const float* __restrict__ Who,
    const float* __restrict__ g1, const float* __restrict__ g2,
    const int* __restrict__ cnt, const int* __restrict__ nbr,
    void* __restrict__ out)
{
    const int n = blockIdx.x;
    const int lane = threadIdx.x;
    const int quad = lane >> 4, l16 = lane & 15;
    __shared__ float sh_s[MAXN];
    __shared__ int sh_m[MAXN];
    const int c0 = cnt[n];
    const int c = (c0 < MAXN) ? c0 : MAXN;
    for (int k = lane; k < c; k += 64) sh_m[k] = nbr[(size_t)n * MAXN + k];
    __syncthreads();
    const float gn = g1[n];
    float mx = -1e30f;
    for (int k = lane; k < c; k += 64) {
        float s = gn + g2[sh_m[k]];
        s = (s >= 0.f) ? s : 0.2f * s;
        sh_s[k] = s;
        mx = fmaxf(mx, s);
    }
#pragma unroll
    for (int off = 32; off; off >>= 1) mx = fmaxf(mx, __shfl_xor(mx, off));
    __syncthreads();
    float sum = 0.f;
    for (int k = lane; k < c; k += 64) {
        float e = __expf(sh_s[k] - mx);
        sh_s[k] = e;
        sum += e;
    }
#pragma unroll
    for (int off = 32; off; off >>= 1) sum += __shfl_xor(sum, off);
    __syncthreads();
    const float inv = (sum > 0.f) ? 1.f / sum : 0.f;
    float accv = 0.f;
#pragma unroll 4
    for (int k = quad; k < c; k += 4)
        accv += sh_s[k] * Who[sh_m[k] * DOUT + l16];
    accv += __shfl_xor(accv, 16);
    accv += __shfl_xor(accv, 32);
    if (quad == 0) {
        float v = accv * inv;
        if (is_f32(adj)) ((float*)out)[n * DOUT + l16] = v;
        else             ((unsigned short*)out)[n * DOUT + l16] = f2us(v);
    }
}

__global__ void wsfail_kernel(float* __restrict__ out)
{
    if (threadIdx.x == 0) out[0] = 129.f;
}

// ---------------------------------------------------------------------------
extern "C" void kernel_launch(void* const* d_in, const int* in_sizes, int n_in,
                              void* d_out, int out_size, void* d_ws, size_t ws_size,
                              hipStream_t stream)
{
    const void* adj = d_in[0];
    const void* X   = d_in[1];
    const void* W   = d_in[2];
    const void* a1  = d_in[3];
    const void* a2  = d_in[4];
    const void* Wo  = d_in[5];
    const void* ao1 = d_in[6];
    const void* ao2 = d_in[7];

    const size_t NEEDED = 22000000;
    if (ws_size < NEEDED) { wsfail_kernel<<<1, 64, 0, stream>>>((float*)d_out); return; }

    int*   cnt  = (int*)d_ws;                        // 4096
    int*   nbr  = cnt + 4096;                        // 4096*512
    float* a1c  = (float*)(nbr + 2097152);           // 512
    float* a2c  = a1c + 512;                         // 512
    float* ao1c = a2c + 512;                         // 16
    float* ao2c = ao1c + 16;                         // 16
    float* f1   = ao2c + 16;                         // 32768
    float* f2   = f1 + 32768;                        // 32768
    float* Who  = f2 + 32768;                        // 65536
    float* g1   = Who + 65536;                       // 4096
    float* g2   = g1 + 4096;                         // 4096
    float* Woc  = g2 + 4096;                         // 8192
    unsigned short* Whb = (unsigned short*)(Woc + 8192);  // 2097152
    unsigned short* Xb  = Whb + 2097152;                  // 2097152
    unsigned short* Wt  = Xb + 2097152;                   // 262144

    prep_nbr_kernel<<<1024 + N_NODES, 256, 0, stream>>>(
        adj, X, W, a1, a2, Wo, ao1, ao2,
        Xb, Wt, Woc, a1c, a2c, ao1c, ao2c, cnt, nbr);
    wh_f12_kernel<<<dim3(NHEADS, N_NODES / 64), 256, 0, stream>>>(
        Xb, Wt, a1c, a2c, Whb, f1, f2);
    attn1_kernel<<<N_NODES, 256, 0, stream>>>(
        Whb, f1, f2, Woc, ao1c, ao2c, cnt, nbr, Who, g1, g2);
    attn2_kernel<<<N_NODES, 64, 0, stream>>>(adj, Who, g1, g2, cnt, nbr, d_out);
}